// Round 1
// baseline (791.629 us; speedup 1.0000x reference)
//
#include <hip/hip_runtime.h>
#include <math.h>

#define NF 39
#define ND 13
#define KDIM 16
#define FEAT 260013
#define NPAIRS (NF * (NF + 1) / 2)   // 780 unordered pairs (i<=j)

// One block per batch sample. Gather-bound kernel:
// cross[b] = sum_{i<38, all j} <W[i][f_j], W[j][f_i]> * xm_i * xm_j
// exploited via symmetry over unordered pairs:
//   i<j<38 : weight 2*xm_i*xm_j   (both (i,j) and (j,i) survive the mask)
//   i==j<38: weight xm_i^2
//   (i,38) i<38: weight xm_i*xm_38 (row 38 is masked, column 38 is not)
//   (38,38): weight 0
__global__ __launch_bounds__(256) void ffm_kernel(
    const float* __restrict__ x,       // [B, 39]
    const float* __restrict__ W,       // [39, FEAT, 16]
    const float* __restrict__ fc_w,    // [FEAT] (trailing dim 1 flattened)
    const float* __restrict__ bias,    // [1]
    const int*   __restrict__ offsets, // [39]
    float* __restrict__ out,           // [B]
    int B)
{
    __shared__ int   sf[NF];
    __shared__ float sxm[NF];
    __shared__ unsigned char spi[NPAIRS];
    __shared__ unsigned char spj[NPAIRS];
    __shared__ float sred[4];

    const int b   = blockIdx.x;
    const int tid = threadIdx.x;

    // Stage per-sample feature indices + multipliers in LDS.
    if (tid < NF) {
        float xv = x[(size_t)b * NF + tid];
        int idx  = (tid < ND) ? 0 : (int)floorf(xv);
        sf[tid]  = idx + offsets[tid];
        sxm[tid] = (tid < ND) ? xv : 1.0f;
    }
    // Triangular pair decode table (cheap VALU; memory-bound kernel).
    for (int p = tid; p < NPAIRS; p += blockDim.x) {
        int i = 0, base = 0;
        while (p >= base + (NF - i)) { base += NF - i; ++i; }
        spi[p] = (unsigned char)i;
        spj[p] = (unsigned char)(i + (p - base));
    }
    __syncthreads();

    float acc = 0.0f;

    // Linear term: 39 scalar gathers, one per thread 0..38.
    if (tid < NF) acc += fc_w[sf[tid]];

    // Pair loop: each thread owns whole pairs; 2 x 64B contiguous loads per pair.
    for (int p = tid; p < NPAIRS; p += blockDim.x) {
        const int i = spi[p];
        const int j = spj[p];
        if (i == NF - 1) continue;  // (38,38): weight 0, skip the loads

        float w;
        if (i == j)            w = sxm[i] * sxm[i];
        else if (j < NF - 1)   w = 2.0f * sxm[i] * sxm[j];
        else                   w = sxm[i] * sxm[j];   // j == 38, i < 38

        const float4* vij = (const float4*)(W + ((size_t)i * FEAT + sf[j]) * KDIM);
        const float4* vji = (const float4*)(W + ((size_t)j * FEAT + sf[i]) * KDIM);

        float d = 0.0f;
        #pragma unroll
        for (int q = 0; q < 4; ++q) {
            float4 a = vij[q];
            float4 c = vji[q];
            d += a.x * c.x + a.y * c.y + a.z * c.z + a.w * c.w;
        }
        acc += w * d;
    }

    // Block reduction: wave64 shuffle, then LDS across the 4 waves.
    #pragma unroll
    for (int off = 32; off > 0; off >>= 1)
        acc += __shfl_down(acc, off, 64);
    if ((tid & 63) == 0) sred[tid >> 6] = acc;
    __syncthreads();

    if (tid == 0) {
        float z = sred[0] + sred[1] + sred[2] + sred[3] + bias[0];
        out[b] = 1.0f / (1.0f + expf(-z));
    }
}

extern "C" void kernel_launch(void* const* d_in, const int* in_sizes, int n_in,
                              void* d_out, int out_size, void* d_ws, size_t ws_size,
                              hipStream_t stream) {
    const float* x       = (const float*)d_in[0];
    const float* W       = (const float*)d_in[1];
    const float* fc_w    = (const float*)d_in[2];
    const float* bias    = (const float*)d_in[3];
    const int*   offsets = (const int*)d_in[4];
    // d_in[5] = n_dense (13), hard-coded as ND

    float* out = (float*)d_out;
    const int B = in_sizes[0] / NF;

    ffm_kernel<<<B, 256, 0, stream>>>(x, W, fc_w, bias, offsets, out, B);
}

// Round 2
// 784.360 us; speedup vs baseline: 1.0093x; 1.0093x over previous
//
#include <hip/hip_runtime.h>
#include <math.h>

#define NF 39
#define ND 13
#define KDIM 16
#define FEAT 260013
#define NPAIRS (NF * (NF + 1) / 2)   // 780 unordered pairs (i<=j)
#define PASSES ((NPAIRS + 31) / 32)  // 25: 32 pairs per 256-thread pass

// One block per sample. Lane-quad-cooperative gather:
//   pair p -> 8 lanes. Lanes [8k..8k+3] load vij = W[i][f_j] (one float4 each,
//   coalesced 64B segment); lanes [8k+4..8k+7] load vji = W[j][f_i].
//   dot computed via __shfl_xor(4); both quads produce it -> weight * 0.5.
// Mask algebra (row i<38 kept, all j):
//   i<j<38 : 2*xm_i*xm_j ; i==j<38 : xm_i^2 ; (i,38) i<38 : xm_i*xm_38 ; (38,38): 0
__global__ __launch_bounds__(256) void ffm_kernel(
    const float* __restrict__ x,       // [B, 39]
    const float* __restrict__ W,       // [39, FEAT, 16]
    const float* __restrict__ fc_w,    // [FEAT]
    const float* __restrict__ bias,    // [1]
    const int*   __restrict__ offsets, // [39]
    float* __restrict__ out,           // [B]
    int B)
{
    __shared__ int            sf[NF];     // global feature index per field
    __shared__ float          sxm[NF];    // multiplier per field
    __shared__ unsigned short spij[NPAIRS];
    __shared__ float          sred[4];

    const int b   = blockIdx.x;
    const int tid = threadIdx.x;

    if (tid < NF) {
        float xv = x[(size_t)b * NF + tid];
        int idx  = (tid < ND) ? 0 : (int)floorf(xv);
        sf[tid]  = idx + offsets[tid];
        sxm[tid] = (tid < ND) ? xv : 1.0f;
    }
    for (int p = tid; p < NPAIRS; p += 256) {
        int i = 0, base = 0;
        while (p >= base + (NF - i)) { base += NF - i; ++i; }
        int j = i + (p - base);
        spij[p] = (unsigned short)(i | (j << 8));
    }
    __syncthreads();

    const int slot = tid >> 3;        // 0..31 : pair slot within pass
    const int quad = (tid >> 2) & 1;  // 0: vij, 1: vji
    const int qi   = tid & 3;         // float4 index within vector

    float acc = 0.0f;
    if (tid < NF) acc += fc_w[sf[tid]];   // linear term

    #pragma unroll 5
    for (int pass = 0; pass < PASSES; ++pass) {
        int p  = pass * 32 + slot;
        int pc = (p < NPAIRS) ? p : (NPAIRS - 1);
        int ij = spij[pc];
        int i  = ij & 0xff;
        int j  = ij >> 8;

        // weight (both quads compute identically); 0 for padding & (38,38)
        float w;
        if (i == j)            w = (i < NF - 1) ? sxm[i] * sxm[i] : 0.0f;
        else if (j < NF - 1)   w = 2.0f * sxm[i] * sxm[j];
        else                   w = sxm[i] * sxm[j];
        if (p >= NPAIRS) w = 0.0f;

        int row  = quad ? j : i;
        int feat = quad ? sf[i] : sf[j];
        const float4* vp = (const float4*)(W + ((size_t)row * FEAT + feat) * KDIM);
        float4 v = vp[qi];

        // partner quad's chunk (vji if I hold vij, and vice versa)
        float4 u;
        u.x = __shfl_xor(v.x, 4, 64);
        u.y = __shfl_xor(v.y, 4, 64);
        u.z = __shfl_xor(v.z, 4, 64);
        u.w = __shfl_xor(v.w, 4, 64);

        float d = v.x * u.x + v.y * u.y + v.z * u.z + v.w * u.w;
        acc += 0.5f * w * d;   // 8 lanes produce 2x the dot
    }

    // block reduction: wave64 shuffle, then LDS across 4 waves
    #pragma unroll
    for (int off = 32; off > 0; off >>= 1)
        acc += __shfl_down(acc, off, 64);
    if ((tid & 63) == 0) sred[tid >> 6] = acc;
    __syncthreads();

    if (tid == 0) {
        float z = sred[0] + sred[1] + sred[2] + sred[3] + bias[0];
        out[b] = 1.0f / (1.0f + expf(-z));
    }
}

extern "C" void kernel_launch(void* const* d_in, const int* in_sizes, int n_in,
                              void* d_out, int out_size, void* d_ws, size_t ws_size,
                              hipStream_t stream) {
    const float* x       = (const float*)d_in[0];
    const float* W       = (const float*)d_in[1];
    const float* fc_w    = (const float*)d_in[2];
    const float* bias    = (const float*)d_in[3];
    const int*   offsets = (const int*)d_in[4];

    float* out = (float*)d_out;
    const int B = in_sizes[0] / NF;

    ffm_kernel<<<B, 256, 0, stream>>>(x, W, fc_w, bias, offsets, out, B);
}